// Round 6
// baseline (2382.252 us; speedup 1.0000x reference)
//
#include <hip/hip_runtime.h>

// ============================================================================
// Wired CfC (NCP) scan, B=256 x T=1024, 3 layers (hid 135/89/32) + final FC.
//
// Round 10: VALUBusy calibration vs static instruction counts (r5/r8/r9 all
// match a sum-over-4-SIMDs reading) shows true per-SIMD VALU util is ~14%:
// the tick is bound by ~65 dwords/lane/tick of VGPR-spill reloads through
// the per-CU L2 share (~2400 cyc of 3640). The spill is unremovable (demand
// 168 vs hard 128-grant; LDS offload saturates the LDS pipe - r8).
// AMORTIZE it instead: weights are identical for all batch rows ->
//   - 128 blocks x 512 threads, each block scans TWO batch rows (2b, 2b+1).
//   - Row-interleaved dots at k-block granularity: each weight block's
//     (possibly spill-reloaded) registers are used for BOTH rows before
//     moving on -> reload traffic per row halves.
//   - 16 blocks/XCD -> per-block L2 share doubles; scratch set 2.1MB/XCD
//     stays L2-resident.
// Per-CU/tick: VALU ~1040 cyc/SIMD, LDS ~1300 cyc, reload ~1200 cyc ->
// tick 1500-1900 cyc. Predict 650-850us; WRITE_SIZE 58.6 -> ~30MB.
// Keeps round-9 DPP tricks: quad_perm x-sharing (lane^2) + pair_sum (lane^1).
// ============================================================================

typedef _Float16 half2v __attribute__((ext_vector_type(2)));
typedef _Float16 half8v __attribute__((ext_vector_type(8)));
typedef int      int4v  __attribute__((ext_vector_type(4)));

#define NBLK   128
#define NTHR   512
#define TSTEPS 1024
#define KPAD   224
#define KHALF  112

struct Ptrs {
    const float* x;
    const unsigned int* msk[3];   // bool in reference -> int32 on device
    const float* W1[3];
    const float* W2[3];
    const float* Wa[3];
    const float* Wb[3];
    const float* b1[3];
    const float* b2[3];
    const float* ba[3];
    const float* bb[3];
    const float* fcW;
    const float* fcb;
};

__device__ __forceinline__ float fexp2(float x) {
#if __has_builtin(__builtin_amdgcn_exp2f)
    return __builtin_amdgcn_exp2f(x);
#else
    return exp2f(x);
#endif
}
__device__ __forceinline__ float frcp(float x) {
#if __has_builtin(__builtin_amdgcn_rcpf)
    return __builtin_amdgcn_rcpf(x);
#else
    return 1.0f / x;
#endif
}
// sigmoid(x) = 1/(1+2^(-x*log2e)); tanh(x) = 2/(1+2^(-2x*log2e)) - 1
__device__ __forceinline__ float fsig(float x) {
    return frcp(1.0f + fexp2(-1.442695041f * x));
}
__device__ __forceinline__ float ftanh(float x) {
    return 2.0f * frcp(1.0f + fexp2(-2.885390082f * x)) - 1.0f;
}

#if __has_builtin(__builtin_amdgcn_fdot2)
#define FD(a, b, c) __builtin_amdgcn_fdot2((a), (b), (c), false)
#else
__device__ __forceinline__ float fd_fallback(half2v a, half2v b, float c) {
    return c + (float)a[0] * (float)b[0] + (float)a[1] * (float)b[1];
}
#define FD(a, b, c) fd_fallback((a), (b), (c))
#endif

__device__ __forceinline__ half2v h2(_Float16 a, _Float16 b) { return half2v{a, b}; }

// quad_perm(2,3,0,1): fetch lane^2's value (unit-partner within quad). VALU.
__device__ __forceinline__ half8v dpp_xor2(half8v v) {
    int4v a = __builtin_bit_cast(int4v, v);
    int4v r;
    r[0] = __builtin_amdgcn_update_dpp(0, a[0], 0x4E, 0xF, 0xF, true);
    r[1] = __builtin_amdgcn_update_dpp(0, a[1], 0x4E, 0xF, 0xF, true);
    r[2] = __builtin_amdgcn_update_dpp(0, a[2], 0x4E, 0xF, 0xF, true);
    r[3] = __builtin_amdgcn_update_dpp(0, a[3], 0x4E, 0xF, 0xF, true);
    return __builtin_bit_cast(half8v, r);
}
// quad_perm(1,0,3,2): x + lane^1's x (K-half pair combine). VALU.
__device__ __forceinline__ float pair_sum(float x) {
    const int v = __builtin_amdgcn_update_dpp(
        0, __builtin_bit_cast(int, x), 0xB1, 0xF, 0xF, true);
    return x + __builtin_bit_cast(float, v);
}

// Fold one (masked) weight pair to f16, zero beyond the real K.
__device__ __forceinline__ half2v fold2(const float* Wp, const unsigned int* mkp,
                                        int nK, int K, int k0) {
    float u0 = 0.f, u1 = 0.f;
    if (k0 < K) {
        const int i0 = nK + k0;
        u0 = Wp[i0] * ((mkp[i0] != 0u) ? 1.0f : 0.0f);
    }
    if (k0 + 1 < K) {
        const int i1 = nK + k0 + 1;
        u1 = Wp[i1] * ((mkp[i1] != 0u) ? 1.0f : 0.0f);
    }
    return h2((_Float16)u0, (_Float16)u1);
}

// 24 dot2s for block-pair m, one row: own blocks xo_, partner blocks xt_,
// accumulating into the named accumulators. Weight uses are adjacent across
// the two row invocations -> one spill-reload serves both rows.
#define DOTS(m, xo_, xt_, A0, A1, B0, B1, C0, C1) { \
    const half2v o0 = h2(xo_[0], xo_[1]), o1 = h2(xo_[2], xo_[3]); \
    const half2v o2 = h2(xo_[4], xo_[5]), o3 = h2(xo_[6], xo_[7]); \
    const half2v t0 = h2(xt_[0], xt_[1]), t1 = h2(xt_[2], xt_[3]); \
    const half2v t2 = h2(xt_[4], xt_[5]), t3 = h2(xt_[6], xt_[7]); \
    A0 = FD(o0, w1o[4*(m)+0], A0);  A1 = FD(t0, w1t[4*(m)+0], A1); \
    B0 = FD(o0, w2o[4*(m)+0], B0);  B1 = FD(t0, w2t[4*(m)+0], B1); \
    C0 = FD(o0, wao[4*(m)+0], C0);  C1 = FD(t0, wat[4*(m)+0], C1); \
    A0 = FD(o1, w1o[4*(m)+1], A0);  A1 = FD(t1, w1t[4*(m)+1], A1); \
    B0 = FD(o1, w2o[4*(m)+1], B0);  B1 = FD(t1, w2t[4*(m)+1], B1); \
    C0 = FD(o1, wao[4*(m)+1], C0);  C1 = FD(t1, wat[4*(m)+1], C1); \
    A0 = FD(o2, w1o[4*(m)+2], A0);  A1 = FD(t2, w1t[4*(m)+2], A1); \
    B0 = FD(o2, w2o[4*(m)+2], B0);  B1 = FD(t2, w2t[4*(m)+2], B1); \
    C0 = FD(o2, wao[4*(m)+2], C0);  C1 = FD(t2, wat[4*(m)+2], C1); \
    A0 = FD(o3, w1o[4*(m)+3], A0);  A1 = FD(t3, w1t[4*(m)+3], A1); \
    B0 = FD(o3, w2o[4*(m)+3], B0);  B1 = FD(t3, w2t[4*(m)+3], B1); \
    C0 = FD(o3, wao[4*(m)+3], C0);  C1 = FD(t3, wat[4*(m)+3], C1); \
}

__global__ __launch_bounds__(NTHR)
__attribute__((amdgpu_waves_per_eu(2, 2)))
void cfc_kernel(Ptrs P, float* __restrict__ out) {
    // xc[row][parity][layer][k] : f16 concat inputs, zero-padded to KPAD.
    __shared__ __align__(16) _Float16 xc[2][2][3][KPAD];
    __shared__ __align__(16) float hn[2][256];

    const int tid  = threadIdx.x;
    const int b    = blockIdx.x;          // block handles rows 2b, 2b+1
    const int unit = tid >> 1;   // output unit 0..255
    const int half = tid & 1;    // which K-half this lane owns
    const int up   = unit & 1;   // block-parity this lane reads itself

    // wave 4 (tid 256..319) contains the layer-straddling quad (units 134/135)
    // -> whole wave takes the direct path (wave-uniform, no divergence).
    const bool direct = ((tid >> 6) == 4);

    // ---- pair role: one output unit ----
    int L, n;
    if (unit < 135)      { L = 0; n = unit; }
    else if (unit < 224) { L = 1; n = unit - 135; }
    else                 { L = 2; n = unit - 224; }
    const int K    = (L == 0) ? 199 : ((L == 1) ? 224 : 121);
    const int HOFF = (L == 0) ? 0   : ((L == 1) ? 135 : 224);

    // ---- zero LDS (padding regions must read as 0.0) ----
    {
        int* z = (int*)&xc[0][0][0][0];
        for (int i = tid; i < 2 * 2 * 3 * KPAD / 2; i += NTHR) z[i] = 0;
    }
    __syncthreads();

    // ---- x staging: threads 384..511 own (row, feature) of the 2x64 slots ----
    const int xlane = tid - 384;          // 0..127 for staging lanes
    const int sr    = (xlane >> 6) & 1;   // staged row (0/1)
    const int sf    = xlane & 63;         // staged feature
    float xpend = 0.0f;
    if (xlane >= 0) {
        const size_t rbase = ((size_t)(2 * b + sr)) * TSTEPS;
        xc[sr][0][0][sf] = (_Float16)P.x[(rbase + 0) * 64 + sf];
        xpend            = P.x[(rbase + 1) * 64 + sf];
    }

    // ---- weight preload: own/other block order; fold mask, fold Wa+Wb ----
    const float* W1p        = P.W1[L];
    const float* W2p        = P.W2[L];
    const float* Wap        = P.Wa[L];
    const float* Wbp        = P.Wb[L];
    const unsigned int* mkp = P.msk[L];
    const int nK   = n * K;
    const int koff = half * KHALF;

    half2v w1o[28], w1t[28], w2o[28], w2t[28], wao[28], wat[28];
#pragma unroll
    for (int m = 0; m < 7; ++m) {
#pragma unroll
        for (int j = 0; j < 4; ++j) {
            const int ko = koff + (2 * m + up) * 8 + 2 * j;      // own block
            const int kt = koff + (2 * m + 1 - up) * 8 + 2 * j;  // partner block
            w1o[m * 4 + j] = fold2(W1p, mkp, nK, K, ko);
            w1t[m * 4 + j] = fold2(W1p, mkp, nK, K, kt);
            w2o[m * 4 + j] = fold2(W2p, mkp, nK, K, ko);
            w2t[m * 4 + j] = fold2(W2p, mkp, nK, K, kt);
            {
                float a0 = 0.f, a1 = 0.f;
                if (ko < K)     a0 = Wap[nK + ko] + Wbp[nK + ko];
                if (ko + 1 < K) a1 = Wap[nK + ko + 1] + Wbp[nK + ko + 1];
                wao[m * 4 + j] = h2((_Float16)a0, (_Float16)a1);
            }
            {
                float a0 = 0.f, a1 = 0.f;
                if (kt < K)     a0 = Wap[nK + kt] + Wbp[nK + kt];
                if (kt + 1 < K) a1 = Wap[nK + kt + 1] + Wbp[nK + kt + 1];
                wat[m * 4 + j] = h2((_Float16)a0, (_Float16)a1);
            }
        }
    }
    const float bv1 = P.b1[L][n];
    const float bv2 = P.b2[L][n];
    const float bva = P.ba[L][n] + P.bb[L][n];
    __syncthreads();

    // ---- main scan: layer L computes timestep (tick - L); 1 barrier/tick ----
    for (int tick = 0; tick < TSTEPS + 2; ++tick) {
        // stage x(tick+1) (loaded 1 tick ago), prefetch x(tick+2)
        if (xlane >= 0) {
            if (tick + 1 < TSTEPS)
                xc[sr][(tick + 1) & 1][0][sf] = (_Float16)xpend;
            if (tick + 2 < TSTEPS)
                xpend = P.x[(((size_t)(2 * b + sr)) * TSTEPS + (tick + 2)) * 64 + sf];
        }

        const int s = tick - L;
        if (s >= 0 && s < TSTEPS) {
            const _Float16* s0 = &xc[0][s & 1][L][koff];
            const _Float16* s1 = &xc[1][s & 1][L][koff];
            const _Float16* po0 = s0 + up * 8;
            const _Float16* pt0 = s0 + (1 - up) * 8;
            const _Float16* po1 = s1 + up * 8;
            const _Float16* pt1 = s1 + (1 - up) * 8;
            float r000 = 0.f, r001 = 0.f, r010 = 0.f, r011 = 0.f, r020 = 0.f, r021 = 0.f;
            float r100 = 0.f, r101 = 0.f, r110 = 0.f, r111 = 0.f, r120 = 0.f, r121 = 0.f;
            if (!direct) {
                // read 7 blocks per row; partner 7 via DPP (VALU, not LDS)
#pragma unroll
                for (int m = 0; m < 7; ++m) {
                    const half8v x0o = *(const half8v*)(po0 + m * 16);
                    const half8v x0t = dpp_xor2(x0o);
                    const half8v x1o = *(const half8v*)(po1 + m * 16);
                    const half8v x1t = dpp_xor2(x1o);
                    DOTS(m, x0o, x0t, r000, r001, r010, r011, r020, r021);
                    DOTS(m, x1o, x1t, r100, r101, r110, r111, r120, r121);
                }
            } else {
                // wave 4: direct 14-block read (contains mixed-layer quad)
#pragma unroll
                for (int m = 0; m < 7; ++m) {
                    const half8v x0o = *(const half8v*)(po0 + m * 16);
                    const half8v x0t = *(const half8v*)(pt0 + m * 16);
                    const half8v x1o = *(const half8v*)(po1 + m * 16);
                    const half8v x1t = *(const half8v*)(pt1 + m * 16);
                    DOTS(m, x0o, x0t, r000, r001, r010, r011, r020, r021);
                    DOTS(m, x1o, x1t, r100, r101, r110, r111, r120, r121);
                }
            }

            const int pA = s & 1;        // consumer at timestep s (next layer)
            const int pB = (s + 1) & 1;  // consumer at timestep s+1 (own recurrence)

            // ---- row 0 ----
            {
                const float s1v = pair_sum(r000 + r001);
                const float s2v = pair_sum(r010 + r011);
                const float sav = pair_sum(r020 + r021);
                const float f1 = ftanh(s1v + bv1);
                const float f2 = ftanh(s2v + bv2);
                const float tg = fsig(sav + bva);
                const float h  = f1 + tg * (f2 - f1);
                const _Float16 hv = (_Float16)h;
                if (half == 0) {
                    if (L == 0)      xc[0][pA][1][n] = hv;
                    else if (L == 1) xc[0][pA][2][n] = hv;
                    if (s == TSTEPS - 1) hn[0][HOFF + n] = h;
                } else {
                    if (L == 0)      xc[0][pB][0][64 + n]  = hv;
                    else if (L == 1) xc[0][pB][1][135 + n] = hv;
                    else             xc[0][pB][2][89 + n]  = hv;
                }
            }
            // ---- row 1 ----
            {
                const float s1v = pair_sum(r100 + r101);
                const float s2v = pair_sum(r110 + r111);
                const float sav = pair_sum(r120 + r121);
                const float f1 = ftanh(s1v + bv1);
                const float f2 = ftanh(s2v + bv2);
                const float tg = fsig(sav + bva);
                const float h  = f1 + tg * (f2 - f1);
                const _Float16 hv = (_Float16)h;
                if (half == 0) {
                    if (L == 0)      xc[1][pA][1][n] = hv;
                    else if (L == 1) xc[1][pA][2][n] = hv;
                    if (s == TSTEPS - 1) hn[1][HOFF + n] = h;
                } else {
                    if (L == 0)      xc[1][pB][0][64 + n]  = hv;
                    else if (L == 1) xc[1][pB][1][135 + n] = hv;
                    else             xc[1][pB][2][89 + n]  = hv;
                }
            }
        }
        __syncthreads();
    }

    // ---- FC epilogue: out[r][o] = dot(hn[r], fcW[o,:]) + fcb[o], pair-split ----
#pragma unroll
    for (int r = 0; r < 2; ++r) {
        const int o = unit;
        const float4* wr = (const float4*)(P.fcW + (size_t)o * 256 + half * 128);
        const float4* hr = (const float4*)(&hn[r][0] + half * 128);
        float acc = half ? 0.0f : P.fcb[o];
#pragma unroll 8
        for (int d = 0; d < 32; ++d) {
            const float4 a = hr[d];
            const float4 w = wr[d];
            acc += a.x * w.x + a.y * w.y + a.z * w.z + a.w * w.w;
        }
        acc = pair_sum(acc);
        if (half == 0) out[((size_t)(2 * b + r)) * 256 + o] = acc;
    }
}

extern "C" void kernel_launch(void* const* d_in, const int* in_sizes, int n_in,
                              void* d_out, int out_size, void* d_ws, size_t ws_size,
                              hipStream_t stream) {
    (void)in_sizes; (void)n_in; (void)out_size; (void)d_ws; (void)ws_size;
    Ptrs P;
    P.x = (const float*)d_in[0];
    for (int l = 0; l < 3; ++l) {
        const int base = 1 + l * 9;
        P.msk[l] = (const unsigned int*)d_in[base + 0];
        P.W1[l]  = (const float*)d_in[base + 1];
        P.W2[l]  = (const float*)d_in[base + 2];
        P.Wa[l]  = (const float*)d_in[base + 3];
        P.Wb[l]  = (const float*)d_in[base + 4];
        P.b1[l]  = (const float*)d_in[base + 5];
        P.b2[l]  = (const float*)d_in[base + 6];
        P.ba[l]  = (const float*)d_in[base + 7];
        P.bb[l]  = (const float*)d_in[base + 8];
    }
    P.fcW = (const float*)d_in[28];
    P.fcb = (const float*)d_in[29];

    hipLaunchKernelGGL(cfc_kernel, dim3(NBLK), dim3(NTHR), 0, stream,
                       P, (float*)d_out);
}

// Round 7
// 1635.887 us; speedup vs baseline: 1.4562x; 1.4562x over previous
//
#include <hip/hip_runtime.h>

// ============================================================================
// Wired CfC (NCP) scan, B=256 x T=1024, 3 layers (hid 135/89/32) + final FC.
//
// Round 11: make register pressure PER-WAVE-PATH instead of uniform.
// Spill is local to high-pressure code regions, so clone the scan per layer
// (wave-uniform branches, identical barrier counts -> legal syncthreads):
//  - L0 (units 0-127, waves 0-3): x-part precomputed into LDS U (windowed,
//    WIN=64, in-kernel; x is non-recurrent!) -> scan K drops 199->135
//    (h-part only, mask-free: recurrent block of the mask is all-ones).
//    W1h/W2h = 72 half2 in regs, Wa(h) in LDS -> ZERO spill.
//  - generic (units 128-223, waves 4-6): W1/W2 regs (112), Wa in LDS ->
//    ~15-dword spill, 11KB/CU scratch = L1-resident reloads (was 108KB L2).
//  - L2 (units 224-255, wave 7): K=121 -> 64 half2 + Wa-LDS -> zero spill.
// LDS ~156KB: xc 2.7K + hn 1K + U 48K + wa0 38K + wa1 58K + xwin 8K.
// Predict: WRITE_SIZE 58.6MB -> <15MB, dur 1556 -> 900-1150us.
// ============================================================================

typedef _Float16 half2v __attribute__((ext_vector_type(2)));
typedef _Float16 half8v __attribute__((ext_vector_type(8)));

#define NBLK   256
#define NTHR   512
#define TSTEPS 1024
#define KPAD   224
#define WIN    64

struct Ptrs {
    const float* x;
    const unsigned int* msk[3];
    const float* W1[3];
    const float* W2[3];
    const float* Wa[3];
    const float* Wb[3];
    const float* b1[3];
    const float* b2[3];
    const float* ba[3];
    const float* bb[3];
    const float* fcW;
    const float* fcb;
};

__device__ __forceinline__ float fexp2(float x) {
#if __has_builtin(__builtin_amdgcn_exp2f)
    return __builtin_amdgcn_exp2f(x);
#else
    return exp2f(x);
#endif
}
__device__ __forceinline__ float frcp(float x) {
#if __has_builtin(__builtin_amdgcn_rcpf)
    return __builtin_amdgcn_rcpf(x);
#else
    return 1.0f / x;
#endif
}
__device__ __forceinline__ float fsig(float x) {
    return frcp(1.0f + fexp2(-1.442695041f * x));
}
__device__ __forceinline__ float ftanh(float x) {
    return 2.0f * frcp(1.0f + fexp2(-2.885390082f * x)) - 1.0f;
}

#if __has_builtin(__builtin_amdgcn_fdot2)
#define FD(a, b, c) __builtin_amdgcn_fdot2((a), (b), (c), false)
#else
__device__ __forceinline__ float fd_fallback(half2v a, half2v b, float c) {
    return c + (float)a[0] * (float)b[0] + (float)a[1] * (float)b[1];
}
#define FD(a, b, c) fd_fallback((a), (b), (c))
#endif

__device__ __forceinline__ half2v h2(_Float16 a, _Float16 b) { return half2v{a, b}; }

__device__ __forceinline__ float psum(float x) { return x + __shfl_xor(x, 1, 64); }

// One precompute job: x-part dot for layer-0 unit jn, matrix jm, all WIN ticks.
#define DOJOB(jj_) { \
    const int jm = (jj_) >> 7, jn = (jj_) & 127; \
    const float* Wp = (jm == 0) ? P.W1[0] : (jm == 1) ? P.W2[0] : P.Wa[0]; \
    const float* Wq = P.Wb[0]; \
    const unsigned int* mk0 = P.msk[0]; \
    const int base = jn * 199; \
    half2v wrow[32]; \
    _Pragma("unroll") \
    for (int i2 = 0; i2 < 32; ++i2) { \
        const int k = 2 * i2; \
        float v0 = Wp[base + k], v1 = Wp[base + k + 1]; \
        if (jm == 2) { v0 += Wq[base + k]; v1 += Wq[base + k + 1]; } \
        else { \
            v0 = (mk0[base + k] != 0u) ? v0 : 0.0f; \
            v1 = (mk0[base + k + 1] != 0u) ? v1 : 0.0f; \
        } \
        wrow[i2] = h2((_Float16)v0, (_Float16)v1); \
    } \
    for (int ti = 0; ti < WIN; ++ti) { \
        float acc = 0.0f; \
        _Pragma("unroll") \
        for (int q = 0; q < 8; ++q) { \
            const half8v xq = *(const half8v*)&xwin[ti][8 * q]; \
            acc = FD(h2(xq[0], xq[1]), wrow[4 * q + 0], acc); \
            acc = FD(h2(xq[2], xq[3]), wrow[4 * q + 1], acc); \
            acc = FD(h2(xq[4], xq[5]), wrow[4 * q + 2], acc); \
            acc = FD(h2(xq[6], xq[7]), wrow[4 * q + 3], acc); \
        } \
        U[jm][ti][jn] = (_Float16)acc; \
    } \
}

// Window block: 3 barriers in every clone (equal counts across waves).
#define WINDOW_BLOCK(STAGE_, JOBS_) \
    if ((tick & (WIN - 1)) == 0 && tick < TSTEPS) { \
        __syncthreads(); \
        STAGE_ \
        __syncthreads(); \
        JOBS_ \
        __syncthreads(); \
    }

__global__ __launch_bounds__(NTHR)
void cfc_kernel(Ptrs P, float* __restrict__ out) {
    __shared__ __align__(16) _Float16 xc[2][3][KPAD];     //   2688 B
    __shared__ __align__(16) float    hn[256];            //   1024 B
    __shared__ __align__(16) _Float16 U[3][WIN][128];     //  49152 B
    __shared__ __align__(16) _Float16 wa0[128][152];      //  38912 B (L0 h-part)
    __shared__ __align__(16) _Float16 wa1[128][232];      //  59392 B (units 128-255)
    __shared__ __align__(16) _Float16 xwin[WIN][64];      //   8192 B

    const int tid  = threadIdx.x;
    const int b    = blockIdx.x;
    const int unit = tid >> 1;
    const int half = tid & 1;

    // ---- zero xc (common) ----
    {
        int* z = (int*)&xc[0][0][0];
        for (int i = tid; i < 2 * 3 * KPAD / 2; i += NTHR) z[i] = 0;
    }
    __syncthreads();   // barrier #1 (common)

    const size_t rb = (size_t)b * TSTEPS;

    if (tid < 256) {
        // ====================== CLONE 0: pure L0, units 0-127 ======================
        const int n = unit;
        const float* W1p = P.W1[0];
        const float* W2p = P.W2[0];
        const float* Wap = P.Wa[0];
        const float* Wbp = P.Wb[0];
        const int nK = n * 199;

        // h-part weights (cols 64..198; mask==1 there). 72 elems/lane.
        half2v w1h[36], w2h[36];
#pragma unroll
        for (int i = 0; i < 36; ++i) {
            const int c = 64 + 72 * half + 2 * i;
            float u0 = (c < 199)     ? W1p[nK + c]     : 0.0f;
            float u1 = (c + 1 < 199) ? W1p[nK + c + 1] : 0.0f;
            float v0 = (c < 199)     ? W2p[nK + c]     : 0.0f;
            float v1 = (c + 1 < 199) ? W2p[nK + c + 1] : 0.0f;
            w1h[i] = h2((_Float16)u0, (_Float16)u1);
            w2h[i] = h2((_Float16)v0, (_Float16)v1);
            float a0 = (c < 199)     ? Wap[nK + c] + Wbp[nK + c]         : 0.0f;
            float a1 = (c + 1 < 199) ? Wap[nK + c + 1] + Wbp[nK + c + 1] : 0.0f;
            *(half2v*)&wa0[n][72 * half + 2 * i] = h2((_Float16)a0, (_Float16)a1);
        }
        const float bv1 = P.b1[0][n];
        const float bv2 = P.b2[0][n];
        const float bva = P.ba[0][n] + P.bb[0][n];
        __syncthreads();   // barrier #2

        for (int tick = 0; tick < TSTEPS + 2; ++tick) {
            WINDOW_BLOCK(
                if (tid < 64) {
                    for (int ti = 0; ti < WIN; ++ti)
                        xwin[ti][tid] = (_Float16)P.x[(rb + tick + ti) * 64 + tid];
                },
                { DOJOB(tid); if (tid < 64) { DOJOB(320 + tid); } }
            )
            const int s = tick;
            if (s < TSTEPS) {
                const _Float16* srcp = &xc[s & 1][0][64 + 72 * half];
                const _Float16* wvp  = &wa0[n][72 * half];
                float a0 = 0.f, a1 = 0.f, b0 = 0.f, b1 = 0.f, c0 = 0.f, c1 = 0.f;
#pragma unroll
                for (int kb = 0; kb < 9; ++kb) {
                    const half8v xv = *(const half8v*)(srcp + kb * 8);
                    const half8v wv = *(const half8v*)(wvp + kb * 8);
                    const half2v x0 = h2(xv[0], xv[1]), x1 = h2(xv[2], xv[3]);
                    const half2v x2 = h2(xv[4], xv[5]), x3 = h2(xv[6], xv[7]);
                    a0 = FD(x0, w1h[kb * 4 + 0], a0); b0 = FD(x0, w2h[kb * 4 + 0], b0);
                    c0 = FD(x0, h2(wv[0], wv[1]), c0);
                    a1 = FD(x1, w1h[kb * 4 + 1], a1); b1 = FD(x1, w2h[kb * 4 + 1], b1);
                    c1 = FD(x1, h2(wv[2], wv[3]), c1);
                    a0 = FD(x2, w1h[kb * 4 + 2], a0); b0 = FD(x2, w2h[kb * 4 + 2], b0);
                    c0 = FD(x2, h2(wv[4], wv[5]), c0);
                    a1 = FD(x3, w1h[kb * 4 + 3], a1); b1 = FD(x3, w2h[kb * 4 + 3], b1);
                    c1 = FD(x3, h2(wv[6], wv[7]), c1);
                }
                const int tw = s & (WIN - 1);
                const float u1 = (float)U[0][tw][n];
                const float u2 = (float)U[1][tw][n];
                const float ua = (float)U[2][tw][n];
                const float s1 = psum(a0 + a1) + u1 + bv1;
                const float s2 = psum(b0 + b1) + u2 + bv2;
                const float sa = psum(c0 + c1) + ua + bva;
                const float f1 = ftanh(s1);
                const float f2 = ftanh(s2);
                const float tg = fsig(sa);
                const float h  = f1 + tg * (f2 - f1);
                const _Float16 hv = (_Float16)h;
                const int pA = s & 1, pB = (s + 1) & 1;
                if (half == 0) {
                    xc[pA][1][n] = hv;                     // -> layer1 input
                    if (s == TSTEPS - 1) hn[n] = h;
                } else {
                    xc[pB][0][64 + n] = hv;                // own recurrence
                }
            }
            __syncthreads();
        }
    } else if (tid < 448) {
        // ================== CLONE 1: generic, units 128-223 (L0 tail + L1) ==================
        int L, n;
        if (unit < 135) { L = 0; n = unit; } else { L = 1; n = unit - 135; }
        const int K    = (L == 0) ? 199 : 224;
        const int HOFF = (L == 0) ? 0 : 135;
        const float* W1p = P.W1[L];
        const float* W2p = P.W2[L];
        const float* Wap = P.Wa[L];
        const float* Wbp = P.Wb[L];
        const unsigned int* mkp = P.msk[L];
        const int nK   = n * K;
        const int koff = 112 * half;
        const int u128 = unit - 128;

        half2v wr1[56], wr2[56];
#pragma unroll
        for (int i = 0; i < 56; ++i) {
            const int k0 = koff + 2 * i, k1 = k0 + 1;
            float u0 = 0.f, u1 = 0.f, v0 = 0.f, v1 = 0.f, a0 = 0.f, a1 = 0.f;
            if (k0 < K) {
                const int idx = nK + k0;
                const float mm = (mkp[idx] != 0u) ? 1.0f : 0.0f;
                u0 = W1p[idx] * mm; v0 = W2p[idx] * mm;
                a0 = Wap[idx] + Wbp[idx];
            }
            if (k1 < K) {
                const int idx = nK + k1;
                const float mm = (mkp[idx] != 0u) ? 1.0f : 0.0f;
                u1 = W1p[idx] * mm; v1 = W2p[idx] * mm;
                a1 = Wap[idx] + Wbp[idx];
            }
            wr1[i] = h2((_Float16)u0, (_Float16)u1);
            wr2[i] = h2((_Float16)v0, (_Float16)v1);
            *(half2v*)&wa1[u128][k0] = h2((_Float16)a0, (_Float16)a1);
        }
        const float bv1 = P.b1[L][n];
        const float bv2 = P.b2[L][n];
        const float bva = P.ba[L][n] + P.bb[L][n];
        __syncthreads();   // barrier #2

        for (int tick = 0; tick < TSTEPS + 2; ++tick) {
            WINDOW_BLOCK(;, ;)
            const int s = tick - L;
            if (s >= 0 && s < TSTEPS) {
                const _Float16* srcp = &xc[s & 1][L][koff];
                const _Float16* wvp  = &wa1[u128][koff];
                float a0 = 0.f, a1 = 0.f, b0 = 0.f, b1 = 0.f, c0 = 0.f, c1 = 0.f;
#pragma unroll
                for (int kb = 0; kb < 14; ++kb) {
                    const half8v xv = *(const half8v*)(srcp + kb * 8);
                    const half8v wv = *(const half8v*)(wvp + kb * 8);
                    const half2v x0 = h2(xv[0], xv[1]), x1 = h2(xv[2], xv[3]);
                    const half2v x2 = h2(xv[4], xv[5]), x3 = h2(xv[6], xv[7]);
                    a0 = FD(x0, wr1[kb * 4 + 0], a0); b0 = FD(x0, wr2[kb * 4 + 0], b0);
                    c0 = FD(x0, h2(wv[0], wv[1]), c0);
                    a1 = FD(x1, wr1[kb * 4 + 1], a1); b1 = FD(x1, wr2[kb * 4 + 1], b1);
                    c1 = FD(x1, h2(wv[2], wv[3]), c1);
                    a0 = FD(x2, wr1[kb * 4 + 2], a0); b0 = FD(x2, wr2[kb * 4 + 2], b0);
                    c0 = FD(x2, h2(wv[4], wv[5]), c0);
                    a1 = FD(x3, wr1[kb * 4 + 3], a1); b1 = FD(x3, wr2[kb * 4 + 3], b1);
                    c1 = FD(x3, h2(wv[6], wv[7]), c1);
                }
                const float s1 = psum(a0 + a1) + bv1;
                const float s2 = psum(b0 + b1) + bv2;
                const float sa = psum(c0 + c1) + bva;
                const float f1 = ftanh(s1);
                const float f2 = ftanh(s2);
                const float tg = fsig(sa);
                const float h  = f1 + tg * (f2 - f1);
                const _Float16 hv = (_Float16)h;
                const int pA = s & 1, pB = (s + 1) & 1;
                if (half == 0) {
                    if (L == 0) xc[pA][1][n] = hv; else xc[pA][2][n] = hv;
                    if (s == TSTEPS - 1) hn[HOFF + n] = h;
                } else {
                    if (L == 0) xc[pB][0][64 + n] = hv; else xc[pB][1][135 + n] = hv;
                }
            }
            __syncthreads();
        }
    } else {
        // ====================== CLONE 2: pure L2, units 224-255 ======================
        const int n = unit - 224;                 // 0..31
        const float* W1p = P.W1[2];
        const float* W2p = P.W2[2];
        const float* Wap = P.Wa[2];
        const float* Wbp = P.Wb[2];
        const unsigned int* mkp = P.msk[2];
        const int nK   = n * 121;
        const int koff = 64 * half;
        const int u128 = unit - 128;              // 96..127

        half2v w1q[32], w2q[32];
#pragma unroll
        for (int i = 0; i < 32; ++i) {
            const int k0 = koff + 2 * i, k1 = k0 + 1;
            float u0 = 0.f, u1 = 0.f, v0 = 0.f, v1 = 0.f, a0 = 0.f, a1 = 0.f;
            if (k0 < 121) {
                const int idx = nK + k0;
                const float mm = (mkp[idx] != 0u) ? 1.0f : 0.0f;
                u0 = W1p[idx] * mm; v0 = W2p[idx] * mm;
                a0 = Wap[idx] + Wbp[idx];
            }
            if (k1 < 121) {
                const int idx = nK + k1;
                const float mm = (mkp[idx] != 0u) ? 1.0f : 0.0f;
                u1 = W1p[idx] * mm; v1 = W2p[idx] * mm;
                a1 = Wap[idx] + Wbp[idx];
            }
            w1q[i] = h2((_Float16)u0, (_Float16)u1);
            w2q[i] = h2((_Float16)v0, (_Float16)v1);
            *(half2v*)&wa1[u128][k0] = h2((_Float16)a0, (_Float16)a1);
        }
        const float bv1 = P.b1[2][n];
        const float bv2 = P.b2[2][n];
        const float bva = P.ba[2][n] + P.bb[2][n];

        // x staging (wave 7 owns it): init x(0), prefetch x(1)
        const int xlane = tid - 448;
        float xpend = 0.0f;
        xc[0][0][xlane] = (_Float16)P.x[(rb + 0) * 64 + xlane];
        xpend           = P.x[(rb + 1) * 64 + xlane];
        __syncthreads();   // barrier #2

        for (int tick = 0; tick < TSTEPS + 2; ++tick) {
            WINDOW_BLOCK(;, DOJOB(tid - 192);)
            // stage x(tick+1), prefetch x(tick+2)
            if (tick + 1 < TSTEPS)
                xc[(tick + 1) & 1][0][xlane] = (_Float16)xpend;
            if (tick + 2 < TSTEPS)
                xpend = P.x[(rb + (tick + 2)) * 64 + xlane];

            const int s = tick - 2;
            if (s >= 0 && s < TSTEPS) {
                const _Float16* srcp = &xc[s & 1][2][koff];
                const _Float16* wvp  = &wa1[u128][koff];
                float a0 = 0.f, a1 = 0.f, b0 = 0.f, b1 = 0.f, c0 = 0.f, c1 = 0.f;
#pragma unroll
                for (int kb = 0; kb < 8; ++kb) {
                    const half8v xv = *(const half8v*)(srcp + kb * 8);
                    const half8v wv = *(const half8v*)(wvp + kb * 8);
                    const half2v x0 = h2(xv[0], xv[1]), x1 = h2(xv[2], xv[3]);
                    const half2v x2 = h2(xv[4], xv[5]), x3 = h2(xv[6], xv[7]);
                    a0 = FD(x0, w1q[kb * 4 + 0], a0); b0 = FD(x0, w2q[kb * 4 + 0], b0);
                    c0 = FD(x0, h2(wv[0], wv[1]), c0);
                    a1 = FD(x1, w1q[kb * 4 + 1], a1); b1 = FD(x1, w2q[kb * 4 + 1], b1);
                    c1 = FD(x1, h2(wv[2], wv[3]), c1);
                    a0 = FD(x2, w1q[kb * 4 + 2], a0); b0 = FD(x2, w2q[kb * 4 + 2], b0);
                    c0 = FD(x2, h2(wv[4], wv[5]), c0);
                    a1 = FD(x3, w1q[kb * 4 + 3], a1); b1 = FD(x3, w2q[kb * 4 + 3], b1);
                    c1 = FD(x3, h2(wv[6], wv[7]), c1);
                }
                const float s1 = psum(a0 + a1) + bv1;
                const float s2 = psum(b0 + b1) + bv2;
                const float sa = psum(c0 + c1) + bva;
                const float f1 = ftanh(s1);
                const float f2 = ftanh(s2);
                const float tg = fsig(sa);
                const float h  = f1 + tg * (f2 - f1);
                const _Float16 hv = (_Float16)h;
                const int pB = (s + 1) & 1;
                if (half == 0) {
                    if (s == TSTEPS - 1) hn[224 + n] = h;
                } else {
                    xc[pB][2][89 + n] = hv;
                }
            }
            __syncthreads();
        }
    }

    // ---- FC epilogue: out[b][o] = dot(hn, fcW[o,:]) + fcb[o], K-split pair ----
    {
        const int o = unit;
        const float4* wr = (const float4*)(P.fcW + (size_t)o * 256 + half * 128);
        const float4* hr = (const float4*)(hn + half * 128);
        float acc = half ? 0.0f : P.fcb[o];
#pragma unroll 8
        for (int d = 0; d < 32; ++d) {
            const float4 a = hr[d];
            const float4 w = wr[d];
            acc += a.x * w.x + a.y * w.y + a.z * w.z + a.w * w.w;
        }
        acc = psum(acc);
        if (half == 0) out[(size_t)b * 256 + o] = acc;
    }
}

extern "C" void kernel_launch(void* const* d_in, const int* in_sizes, int n_in,
                              void* d_out, int out_size, void* d_ws, size_t ws_size,
                              hipStream_t stream) {
    (void)in_sizes; (void)n_in; (void)out_size; (void)d_ws; (void)ws_size;
    Ptrs P;
    P.x = (const float*)d_in[0];
    for (int l = 0; l < 3; ++l) {
        const int base = 1 + l * 9;
        P.msk[l] = (const unsigned int*)d_in[base + 0];
        P.W1[l]  = (const float*)d_in[base + 1];
        P.W2[l]  = (const float*)d_in[base + 2];
        P.Wa[l]  = (const float*)d_in[base + 3];
        P.Wb[l]  = (const float*)d_in[base + 4];
        P.b1[l]  = (const float*)d_in[base + 5];
        P.b2[l]  = (const float*)d_in[base + 6];
        P.ba[l]  = (const float*)d_in[base + 7];
        P.bb[l]  = (const float*)d_in[base + 8];
    }
    P.fcW = (const float*)d_in[28];
    P.fcb = (const float*)d_in[29];

    hipLaunchKernelGGL(cfc_kernel, dim3(NBLK), dim3(NTHR), 0, stream,
                       P, (float*)d_out);
}